// Round 1
// baseline (3276.843 us; speedup 1.0000x reference)
//
#include <hip/hip_runtime.h>
#include <math.h>

// Problem constants (Gemma3 attention block)
#define BB   2
#define SS   2048
#define EE   2048
#define HH   8
#define KVN  4
#define DD   256
#define WINW 1024
#define EPSV 1e-6f

// ---------------------------------------------------------------------------
// fp32 GEMM: C[M,N] = A[M,K] @ B[K,N], row-major. 128x128 tile, BK=8,
// 256 threads, 8x8 micro-tile per thread. Columns per thread are split as
// {tx*4..+3, 64+tx*4..+3} so LDS B reads are <=2-way conflicts (free).
// ---------------------------------------------------------------------------
__global__ __launch_bounds__(256)
void gemm_f32(const float* __restrict__ A, const float* __restrict__ Bw,
              float* __restrict__ C, int M, int N, int K)
{
    __shared__ float As[8][128];   // As[k][m]
    __shared__ float Bs[8][128];   // Bs[k][n]
    const int t    = threadIdx.x;
    const int bm   = blockIdx.y * 128;
    const int bn   = blockIdx.x * 128;
    const int tx   = t & 15;
    const int ty   = t >> 4;
    const int arow = t >> 1;
    const int ak   = (t & 1) * 4;
    const int brow = t >> 5;
    const int bcol = (t & 31) * 4;
    const float* Ap = A  + (size_t)(bm + arow) * K + ak;
    const float* Bp = Bw + (size_t)brow * N + bn + bcol;

    float acc[8][8];
#pragma unroll
    for (int i = 0; i < 8; ++i)
#pragma unroll
        for (int j = 0; j < 8; ++j) acc[i][j] = 0.f;

    for (int k0 = 0; k0 < K; k0 += 8) {
        const float4 av = *(const float4*)(Ap + k0);
        const float4 bv = *(const float4*)(Bp + (size_t)k0 * N);
        __syncthreads();
        As[ak + 0][arow] = av.x;
        As[ak + 1][arow] = av.y;
        As[ak + 2][arow] = av.z;
        As[ak + 3][arow] = av.w;
        *(float4*)&Bs[brow][bcol] = bv;
        __syncthreads();
#pragma unroll
        for (int kk = 0; kk < 8; ++kk) {
            float ar[8], br[8];
            *(float4*)&ar[0] = *(const float4*)&As[kk][ty * 8];
            *(float4*)&ar[4] = *(const float4*)&As[kk][ty * 8 + 4];
            *(float4*)&br[0] = *(const float4*)&Bs[kk][tx * 4];
            *(float4*)&br[4] = *(const float4*)&Bs[kk][tx * 4 + 64];
#pragma unroll
            for (int i = 0; i < 8; ++i)
#pragma unroll
                for (int j = 0; j < 8; ++j)
                    acc[i][j] = fmaf(ar[i], br[j], acc[i][j]);
        }
    }
#pragma unroll
    for (int i = 0; i < 8; ++i) {
        float* Crow = C + (size_t)(bm + ty * 8 + i) * N + bn;
        *(float4*)(Crow + tx * 4)      = make_float4(acc[i][0], acc[i][1], acc[i][2], acc[i][3]);
        *(float4*)(Crow + 64 + tx * 4) = make_float4(acc[i][4], acc[i][5], acc[i][6], acc[i][7]);
    }
}

// ---------------------------------------------------------------------------
// Fused Gemma-style RMSNorm (scale = 1 + w) + RoPE, in place.
// One wave per row of D=256; 4 rows per 256-thread block.
// `scale` additionally folds the attention q-scale (D^-0.5) for Q.
// ---------------------------------------------------------------------------
template <int NH>
__global__ __launch_bounds__(256)
void rmsnorm_rope(float* __restrict__ x, const float* __restrict__ w,
                  const float* __restrict__ cs, const float* __restrict__ sn,
                  float scale)
{
    const int wv   = threadIdx.x >> 6;
    const int lane = threadIdx.x & 63;
    const int row  = blockIdx.x * 4 + wv;     // (b*S+s)*NH + h
    const int m    = row / NH;                // b*S + s
    float* xr = x + (size_t)row * DD;

    const float4 xv = ((const float4*)xr)[lane];
    float ss = xv.x * xv.x + xv.y * xv.y + xv.z * xv.z + xv.w * xv.w;
#pragma unroll
    for (int d = 1; d < 64; d <<= 1) ss += __shfl_xor(ss, d, 64);
    const float inv = 1.0f / sqrtf(ss * (1.0f / (float)DD) + EPSV);

    const float4 w4 = ((const float4*)w)[lane];
    float4 y;
    y.x = xv.x * inv * (1.f + w4.x);
    y.y = xv.y * inv * (1.f + w4.y);
    y.z = xv.z * inv * (1.f + w4.z);
    y.w = xv.w * inv * (1.f + w4.w);

    __shared__ float4 buf[4][64];
    buf[wv][lane] = y;
    __syncthreads();
    const float4 r0 = buf[wv][(lane < 32) ? (lane + 32) : (lane - 32)];
    float4 rot;
    if (lane < 32) { rot.x = -r0.x; rot.y = -r0.y; rot.z = -r0.z; rot.w = -r0.w; }
    else           { rot = r0; }

    const float4 c4 = ((const float4*)(cs + (size_t)m * DD))[lane];
    const float4 s4 = ((const float4*)(sn + (size_t)m * DD))[lane];
    float4 o;
    o.x = (y.x * c4.x + rot.x * s4.x) * scale;
    o.y = (y.y * c4.y + rot.y * s4.y) * scale;
    o.z = (y.z * c4.z + rot.z * s4.z) * scale;
    o.w = (y.w * c4.w + rot.w * s4.w) * scale;
    ((float4*)xr)[lane] = o;
}

// ---------------------------------------------------------------------------
// Flash-style sliding-window GQA attention, fp32.
// Block = 256 threads (4 waves) handles one (b, h, 32-row q tile).
// Dim-split: wave wd owns dims [wd*64, wd*64+64). Each wave computes a
// partial 32x32 score tile over its dims (4x4 per thread), partials are
// reduced through LDS, softmax is computed redundantly per wave, and PV
// accumulates each wave's own dim chunk. K/V tiles are staged in LDS with
// an f4 XOR swizzle (key = (row>>2)&7) making every ds_read_b128 pattern
// conflict-free. P is broadcast via __shfl (no LDS P buffer, no extra sync).
// Output is written IN PLACE into the q buffer (disjoint row ownership).
// ---------------------------------------------------------------------------
__global__ __launch_bounds__(256)
void attn_fwd(const float* __restrict__ q, const float* __restrict__ k,
              const float* __restrict__ v, const int* __restrict__ am,
              float* __restrict__ o)
{
    const int qt  = blockIdx.x;
    const int h   = blockIdx.y;
    const int b   = blockIdx.z;
    const int kvh = h >> 1;            // H/KV = 2
    const int q0  = qt * 32;

    __shared__ float4 Qs[32 * 64];
    __shared__ float4 Ks[32 * 64];
    __shared__ float4 Vs[32 * 64];
    __shared__ __align__(16) float Sp[4][32][36];   // partial scores, padded

    const int t    = threadIdx.x;
    const int wd   = t >> 6;           // wave id: dim chunk
    const int lane = t & 63;
    const int rg   = lane >> 3;        // row group: rows rg*4..+3
    const int jg   = lane & 7;         // col group: cols jg*4..+3

    // ---- stage Q (swizzled) ----
#pragma unroll
    for (int c = 0; c < 8; ++c) {
        const int row = c * 4 + wd;
        const float4* src = (const float4*)(q + (((size_t)(b * SS + q0 + row)) * HH + h) * DD);
        Qs[row * 64 + (lane ^ ((row >> 2) & 7))] = src[lane];
    }

    float4 accv[4][2];
    float  m_r[4], l_r[4];
#pragma unroll
    for (int rr = 0; rr < 4; ++rr) {
        accv[rr][0] = make_float4(0.f, 0.f, 0.f, 0.f);
        accv[rr][1] = make_float4(0.f, 0.f, 0.f, 0.f);
        m_r[rr] = -1e30f;
        l_r[rr] = 0.f;
    }

    int jlo = q0 - (WINW - 1);
    if (jlo < 0) jlo = 0;
    const int kt0 = jlo >> 5;
    const int kt1 = (q0 + 31) >> 5;

    for (int kt = kt0; kt <= kt1; ++kt) {
        const int k0 = kt * 32;
        __syncthreads();   // A: previous tile's LDS reads all done
        // ---- stage K,V tile (swizzled) ----
#pragma unroll
        for (int c = 0; c < 8; ++c) {
            const int row = c * 4 + wd;
            const size_t gb = (((size_t)(b * SS + k0 + row)) * KVN + kvh) * DD;
            const int dst = row * 64 + (lane ^ ((row >> 2) & 7));
            Ks[dst] = ((const float4*)(k + gb))[lane];
            Vs[dst] = ((const float4*)(v + gb))[lane];
        }
        __syncthreads();   // B: staging visible

        // ---- partial scores over this wave's 64 dims ----
        float sc[4][4];
#pragma unroll
        for (int rr = 0; rr < 4; ++rr)
#pragma unroll
            for (int jc = 0; jc < 4; ++jc) sc[rr][jc] = 0.f;

#pragma unroll
        for (int d4 = 0; d4 < 16; ++d4) {
            const int qf = wd * 16 + d4;
            float4 qv[4], kv[4];
#pragma unroll
            for (int rr = 0; rr < 4; ++rr) qv[rr] = Qs[(rg * 4 + rr) * 64 + (qf ^ rg)];
#pragma unroll
            for (int jc = 0; jc < 4; ++jc) kv[jc] = Ks[(jg * 4 + jc) * 64 + (qf ^ jg)];
#pragma unroll
            for (int rr = 0; rr < 4; ++rr)
#pragma unroll
                for (int jc = 0; jc < 4; ++jc) {
                    sc[rr][jc] = fmaf(qv[rr].x, kv[jc].x, sc[rr][jc]);
                    sc[rr][jc] = fmaf(qv[rr].y, kv[jc].y, sc[rr][jc]);
                    sc[rr][jc] = fmaf(qv[rr].z, kv[jc].z, sc[rr][jc]);
                    sc[rr][jc] = fmaf(qv[rr].w, kv[jc].w, sc[rr][jc]);
                }
        }
#pragma unroll
        for (int rr = 0; rr < 4; ++rr)
            *(float4*)&Sp[wd][rg * 4 + rr][jg * 4] =
                make_float4(sc[rr][0], sc[rr][1], sc[rr][2], sc[rr][3]);
        __syncthreads();   // C: partials visible

        // ---- reduce partials (identical in every wave) ----
        float sf[4][4];
#pragma unroll
        for (int rr = 0; rr < 4; ++rr) {
            const float4 a0 = *(const float4*)&Sp[0][rg * 4 + rr][jg * 4];
            const float4 a1 = *(const float4*)&Sp[1][rg * 4 + rr][jg * 4];
            const float4 a2 = *(const float4*)&Sp[2][rg * 4 + rr][jg * 4];
            const float4 a3 = *(const float4*)&Sp[3][rg * 4 + rr][jg * 4];
            sf[rr][0] = (a0.x + a1.x) + (a2.x + a3.x);
            sf[rr][1] = (a0.y + a1.y) + (a2.y + a3.y);
            sf[rr][2] = (a0.z + a1.z) + (a2.z + a3.z);
            sf[rr][3] = (a0.w + a1.w) + (a2.w + a3.w);
        }

        bool okc[4];
#pragma unroll
        for (int jc = 0; jc < 4; ++jc)
            okc[jc] = (am[b * SS + (k0 + jg * 4 + jc)] != 0);

        // ---- online softmax (per-row stats; redundant across jg lanes/waves) ----
        float p[4][4];
#pragma unroll
        for (int rr = 0; rr < 4; ++rr) {
            const int qi = q0 + rg * 4 + rr;
            float mx = -1e30f;
            bool ok[4];
#pragma unroll
            for (int jc = 0; jc < 4; ++jc) {
                const int jgl = k0 + jg * 4 + jc;
                ok[jc] = okc[jc] && (jgl <= qi) && ((qi - jgl) < WINW);
                const float sv = ok[jc] ? sf[rr][jc] : -1e30f;
                sf[rr][jc] = sv;
                mx = fmaxf(mx, sv);
            }
            mx = fmaxf(mx, __shfl_xor(mx, 1, 64));
            mx = fmaxf(mx, __shfl_xor(mx, 2, 64));
            mx = fmaxf(mx, __shfl_xor(mx, 4, 64));
            const float mnew = fmaxf(m_r[rr], mx);
            const float corr = __expf(m_r[rr] - mnew);
            float ps = 0.f;
#pragma unroll
            for (int jc = 0; jc < 4; ++jc) {
                const float pv = ok[jc] ? __expf(sf[rr][jc] - mnew) : 0.f;
                p[rr][jc] = pv;
                ps += pv;
            }
            ps += __shfl_xor(ps, 1, 64);
            ps += __shfl_xor(ps, 2, 64);
            ps += __shfl_xor(ps, 4, 64);
            l_r[rr] = l_r[rr] * corr + ps;
            m_r[rr] = mnew;
            accv[rr][0].x *= corr; accv[rr][0].y *= corr;
            accv[rr][0].z *= corr; accv[rr][0].w *= corr;
            accv[rr][1].x *= corr; accv[rr][1].y *= corr;
            accv[rr][1].z *= corr; accv[rr][1].w *= corr;
        }

        // ---- PV: acc[r][dims] += P[r][kj] * V[kj][dims]; P via shuffle ----
#pragma unroll
        for (int kjb = 0; kjb < 8; ++kjb) {
#pragma unroll
            for (int jc2 = 0; jc2 < 4; ++jc2) {
                const int kj  = kjb * 4 + jc2;
                const int key = kjb;                   // (kj>>2)&7
                const float4 v0 = Vs[kj * 64 + ((wd * 16 + jg) ^ key)];
                const float4 v1 = Vs[kj * 64 + ((wd * 16 + 8 + jg) ^ key)];
#pragma unroll
                for (int rr = 0; rr < 4; ++rr) {
                    const float pr = __shfl(p[rr][jc2], rg * 8 + kjb, 64);
                    accv[rr][0].x = fmaf(pr, v0.x, accv[rr][0].x);
                    accv[rr][0].y = fmaf(pr, v0.y, accv[rr][0].y);
                    accv[rr][0].z = fmaf(pr, v0.z, accv[rr][0].z);
                    accv[rr][0].w = fmaf(pr, v0.w, accv[rr][0].w);
                    accv[rr][1].x = fmaf(pr, v1.x, accv[rr][1].x);
                    accv[rr][1].y = fmaf(pr, v1.y, accv[rr][1].y);
                    accv[rr][1].z = fmaf(pr, v1.z, accv[rr][1].z);
                    accv[rr][1].w = fmaf(pr, v1.w, accv[rr][1].w);
                }
            }
        }
    }

    // ---- epilogue: O = acc / l ----
#pragma unroll
    for (int rr = 0; rr < 4; ++rr) {
        const float il = 1.0f / l_r[rr];
        float* orow = o + (((size_t)(b * SS + q0 + rg * 4 + rr)) * HH + h) * DD;
        float4 o0 = accv[rr][0];
        float4 o1 = accv[rr][1];
        o0.x *= il; o0.y *= il; o0.z *= il; o0.w *= il;
        o1.x *= il; o1.y *= il; o1.z *= il; o1.w *= il;
        ((float4*)orow)[wd * 16 + jg]     = o0;
        ((float4*)orow)[wd * 16 + 8 + jg] = o1;
    }
}

// ---------------------------------------------------------------------------
// Launch
// ---------------------------------------------------------------------------
extern "C" void kernel_launch(void* const* d_in, const int* in_sizes, int n_in,
                              void* d_out, int out_size, void* d_ws, size_t ws_size,
                              hipStream_t stream)
{
    (void)in_sizes; (void)n_in; (void)out_size; (void)ws_size;

    const float* X  = (const float*)d_in[0];
    const float* cs = (const float*)d_in[1];
    const float* sn = (const float*)d_in[2];
    const int*   am = (const int*)d_in[3];
    const float* Wq = (const float*)d_in[4];
    const float* Wk = (const float*)d_in[5];
    const float* Wv = (const float*)d_in[6];
    const float* Wo = (const float*)d_in[7];
    const float* qw = (const float*)d_in[8];
    const float* kw = (const float*)d_in[9];
    float* out = (float*)d_out;

    // workspace: q [B,S,H,D] (later reused as attention output), k, v
    float* qb = (float*)d_ws;
    float* kb = qb + (size_t)BB * SS * HH  * DD;   // + 8,388,608 floats
    float* vb = kb + (size_t)BB * SS * KVN * DD;   // + 4,194,304 floats
    // total 64 MiB of d_ws

    const int M = BB * SS;   // 4096
    dim3 blk(256);

    gemm_f32<<<dim3((HH  * DD) / 128, M / 128), blk, 0, stream>>>(X, Wq, qb, M, HH  * DD, EE);
    gemm_f32<<<dim3((KVN * DD) / 128, M / 128), blk, 0, stream>>>(X, Wk, kb, M, KVN * DD, EE);
    gemm_f32<<<dim3((KVN * DD) / 128, M / 128), blk, 0, stream>>>(X, Wv, vb, M, KVN * DD, EE);

    // RMSNorm + RoPE in place; fold q-scale D^-0.5 = 1/16 into Q.
    rmsnorm_rope<HH ><<<dim3(BB * SS * HH  / 4), blk, 0, stream>>>(qb, qw, cs, sn, 0.0625f);
    rmsnorm_rope<KVN><<<dim3(BB * SS * KVN / 4), blk, 0, stream>>>(kb, kw, cs, sn, 1.0f);

    // attention writes output in place into qb (disjoint row ownership)
    attn_fwd<<<dim3(SS / 32, HH, BB), blk, 0, stream>>>(qb, kb, vb, am, qb);

    // output projection
    gemm_f32<<<dim3(EE / 128, M / 128), blk, 0, stream>>>(qb, Wo, out, M, EE, EE);
}

// Round 2
// 1774.673 us; speedup vs baseline: 1.8464x; 1.8464x over previous
//
#include <hip/hip_runtime.h>
#include <math.h>

#define BB   2
#define SS   2048
#define EE   2048
#define HH   8
#define KVN  4
#define DD   256
#define WINW 1024
#define EPSV 1e-6f

using bf16x8 = __attribute__((ext_vector_type(8))) __bf16;
using f32x4  = __attribute__((ext_vector_type(4))) float;

__device__ __forceinline__ unsigned short f2bf(float f) {
    union { float f; unsigned int u; } c; c.f = f;
    unsigned int u = c.u;
    unsigned int r = (u + 0x7FFFu + ((u >> 16) & 1u)) >> 16;   // RTNE
    return (unsigned short)r;
}

// ---------------------------------------------------------------------------
// fp32 GEMM (unchanged from R1 — measured ~83% of fp32 vector peak)
// ---------------------------------------------------------------------------
__global__ __launch_bounds__(256)
void gemm_f32(const float* __restrict__ A, const float* __restrict__ Bw,
              float* __restrict__ C, int M, int N, int K)
{
    __shared__ float As[8][128];
    __shared__ float Bs[8][128];
    const int t    = threadIdx.x;
    const int bm   = blockIdx.y * 128;
    const int bn   = blockIdx.x * 128;
    const int tx   = t & 15;
    const int ty   = t >> 4;
    const int arow = t >> 1;
    const int ak   = (t & 1) * 4;
    const int brow = t >> 5;
    const int bcol = (t & 31) * 4;
    const float* Ap = A  + (size_t)(bm + arow) * K + ak;
    const float* Bp = Bw + (size_t)brow * N + bn + bcol;

    float acc[8][8];
#pragma unroll
    for (int i = 0; i < 8; ++i)
#pragma unroll
        for (int j = 0; j < 8; ++j) acc[i][j] = 0.f;

    for (int k0 = 0; k0 < K; k0 += 8) {
        const float4 av = *(const float4*)(Ap + k0);
        const float4 bv = *(const float4*)(Bp + (size_t)k0 * N);
        __syncthreads();
        As[ak + 0][arow] = av.x;
        As[ak + 1][arow] = av.y;
        As[ak + 2][arow] = av.z;
        As[ak + 3][arow] = av.w;
        *(float4*)&Bs[brow][bcol] = bv;
        __syncthreads();
#pragma unroll
        for (int kk = 0; kk < 8; ++kk) {
            float ar[8], br[8];
            *(float4*)&ar[0] = *(const float4*)&As[kk][ty * 8];
            *(float4*)&ar[4] = *(const float4*)&As[kk][ty * 8 + 4];
            *(float4*)&br[0] = *(const float4*)&Bs[kk][tx * 4];
            *(float4*)&br[4] = *(const float4*)&Bs[kk][tx * 4 + 64];
#pragma unroll
            for (int i = 0; i < 8; ++i)
#pragma unroll
                for (int j = 0; j < 8; ++j)
                    acc[i][j] = fmaf(ar[i], br[j], acc[i][j]);
        }
    }
#pragma unroll
    for (int i = 0; i < 8; ++i) {
        float* Crow = C + (size_t)(bm + ty * 8 + i) * N + bn;
        *(float4*)(Crow + tx * 4)      = make_float4(acc[i][0], acc[i][1], acc[i][2], acc[i][3]);
        *(float4*)(Crow + 64 + tx * 4) = make_float4(acc[i][4], acc[i][5], acc[i][6], acc[i][7]);
    }
}

// ---------------------------------------------------------------------------
// Fused RMSNorm (scale=1+w) + RoPE; reads fp32, writes bf16 (separate buffer).
// One wave per D=256 row, 4 rows/block. `scale` folds q-scale for Q.
// ---------------------------------------------------------------------------
template <int NH>
__global__ __launch_bounds__(256)
void rmsnorm_rope_bf16(const float* __restrict__ x, unsigned short* __restrict__ out,
                       const float* __restrict__ w,
                       const float* __restrict__ cs, const float* __restrict__ sn,
                       float scale)
{
    const int wv   = threadIdx.x >> 6;
    const int lane = threadIdx.x & 63;
    const int row  = blockIdx.x * 4 + wv;     // (b*S+s)*NH + h
    const int m    = row / NH;                // b*S + s
    const float* xr = x + (size_t)row * DD;

    const float4 xv = ((const float4*)xr)[lane];
    float ss = xv.x * xv.x + xv.y * xv.y + xv.z * xv.z + xv.w * xv.w;
#pragma unroll
    for (int d = 1; d < 64; d <<= 1) ss += __shfl_xor(ss, d, 64);
    const float inv = 1.0f / sqrtf(ss * (1.0f / (float)DD) + EPSV);

    const float4 w4 = ((const float4*)w)[lane];
    float4 y;
    y.x = xv.x * inv * (1.f + w4.x);
    y.y = xv.y * inv * (1.f + w4.y);
    y.z = xv.z * inv * (1.f + w4.z);
    y.w = xv.w * inv * (1.f + w4.w);

    __shared__ float4 buf[4][64];
    buf[wv][lane] = y;
    __syncthreads();
    const float4 r0 = buf[wv][(lane < 32) ? (lane + 32) : (lane - 32)];
    float4 rot;
    if (lane < 32) { rot.x = -r0.x; rot.y = -r0.y; rot.z = -r0.z; rot.w = -r0.w; }
    else           { rot = r0; }

    const float4 c4 = ((const float4*)(cs + (size_t)m * DD))[lane];
    const float4 s4 = ((const float4*)(sn + (size_t)m * DD))[lane];
    ushort4 o4;
    o4.x = f2bf((y.x * c4.x + rot.x * s4.x) * scale);
    o4.y = f2bf((y.y * c4.y + rot.y * s4.y) * scale);
    o4.z = f2bf((y.z * c4.z + rot.z * s4.z) * scale);
    o4.w = f2bf((y.w * c4.w + rot.w * s4.w) * scale);
    ((ushort4*)(out + (size_t)row * DD))[lane] = o4;
}

// ---------------------------------------------------------------------------
// V transpose+convert: vb fp32 [b,s,kv,d] -> Vt bf16 [b,kv,d,s].
// 64x64 tiles through LDS.
// ---------------------------------------------------------------------------
__global__ __launch_bounds__(256)
void v_to_vt(const float* __restrict__ vb, unsigned short* __restrict__ Vt)
{
    __shared__ unsigned short Lt[64][66];
    const int s0 = blockIdx.x * 64, d0 = blockIdx.y * 64;
    const int bkv = blockIdx.z;               // b*KVN + kv
    const int b = bkv >> 2, kv = bkv & 3;
    const int t = threadIdx.x;

    {   // phase 1: load fp32 rows, convert, store row-major bf16
        const int s = t >> 2, dseg = t & 3;
        const float* src = vb + (((size_t)(b * SS + s0 + s) * KVN + kv) * DD) + d0 + dseg * 16;
#pragma unroll
        for (int i = 0; i < 4; ++i) {
            const float4 fv = *(const float4*)(src + i * 4);
            ushort2 p0, p1;
            p0.x = f2bf(fv.x); p0.y = f2bf(fv.y);
            p1.x = f2bf(fv.z); p1.y = f2bf(fv.w);
            *(ushort2*)&Lt[s][dseg * 16 + i * 4]     = p0;
            *(ushort2*)&Lt[s][dseg * 16 + i * 4 + 2] = p1;
        }
    }
    __syncthreads();
    {   // phase 2: gather a column (fixed d), write contiguous s-run
        const int d = t >> 2, sseg = t & 3;
        unsigned short tmp[16];
#pragma unroll
        for (int j = 0; j < 16; ++j) tmp[j] = Lt[sseg * 16 + j][d];
        unsigned short* dst = Vt + ((size_t)bkv * DD + d0 + d) * SS + s0 + sseg * 16;
        *(uint4*)(dst)     = *(uint4*)&tmp[0];
        *(uint4*)(dst + 8) = *(uint4*)&tmp[8];
    }
}

// ---------------------------------------------------------------------------
// bf16 MFMA flash attention, sliding window, GQA.
// Block: 256 thr (4 waves), 64 q-rows (16/wave). K-tile 32 rows.
// Swapped QK^T: S^T = mfma(A=K, B=Q) -> softmax reduce = 2 shfl_xor.
// K in LDS row-major bf16, 16B-chunk XOR swizzle (conflict-free A-frags).
// V from pre-transposed global Vt, staged bf16 [d][j] (conflict-free B-frags).
// P exchanged via per-wave padded LDS (no barrier needed).
// ---------------------------------------------------------------------------
__global__ __launch_bounds__(256, 2)
void attn_mfma(const unsigned short* __restrict__ Qb,
               const unsigned short* __restrict__ Kb,
               const unsigned short* __restrict__ Vt,
               const int* __restrict__ am, float* __restrict__ O)
{
    __shared__ unsigned short Ks[32 * 256];    // [j][d], chunk-swizzled
    __shared__ unsigned short Vts[256 * 32];   // [d][j], chunk-swizzled
    __shared__ unsigned short Pl[4][16 * 40];  // per-wave P, row pad 40
    __shared__ int Ams[32];

    const int t = threadIdx.x, w = t >> 6, l = t & 63;
    const int g = l >> 4, q15 = l & 15;
    const int qb0 = blockIdx.x * 64, h = blockIdx.y, b = blockIdx.z;
    const int kvh = h >> 1;
    const int qrow = qb0 + w * 16 + q15;       // this lane's q (B-frag col)

    // Q B-fragments, register-resident for the whole block
    bf16x8 qf[8];
    {
        const unsigned short* qp = Qb + ((size_t)(b * SS + qrow) * HH + h) * DD + g * 8;
#pragma unroll
        for (int km = 0; km < 8; ++km) qf[km] = *(const bf16x8*)(qp + km * 32);
    }

    f32x4 oacc[16];
#pragma unroll
    for (int i = 0; i < 16; ++i) oacc[i] = (f32x4){0.f, 0.f, 0.f, 0.f};
    float mrow = -1e30f, lrow = 0.f;

    const int qlo = qb0 + w * 16, qhi = qlo + 15;
    int kstart = qb0 - 1024; if (kstart < 0) kstart = 0;
    const int kend = qb0 + 32;

    const int sj = t >> 3, sc = t & 7;         // K staging: row, 64B chunk

    for (int k0 = kstart; k0 <= kend; k0 += 32) {
        // ---- stage K, V, am ----
        {
            const unsigned short* kp = Kb + ((size_t)(b * SS + k0 + sj) * KVN + kvh) * DD + sc * 32;
#pragma unroll
            for (int i = 0; i < 4; ++i) {
                const int cc = sc * 4 + i;
                *(uint4*)&Ks[sj * 256 + ((cc ^ (sj & 7)) * 8)] = *(const uint4*)(kp + i * 8);
            }
#pragma unroll
            for (int it = 0; it < 4; ++it) {
                const int d = it * 64 + (t >> 2), c = t & 3;
                const unsigned short* vp = Vt + ((size_t)(b * KVN + kvh) * DD + d) * SS + k0 + c * 8;
                *(uint4*)&Vts[d * 32 + ((c ^ (d & 3)) * 8)] = *(const uint4*)vp;
            }
            if (t < 32) Ams[t] = am[b * SS + k0 + t];
        }
        __syncthreads();

        // ---- compute (wave-level window guard; barriers stay outside) ----
        if (k0 <= qhi && k0 + 31 >= qlo - (WINW - 1)) {
            float pv[8];
            int   okf[8];
            float tmax = -1e30f;
#pragma unroll
            for (int jb = 0; jb < 2; ++jb) {
                f32x4 sacc = (f32x4){0.f, 0.f, 0.f, 0.f};
                const int krow = jb * 16 + q15;
                const unsigned short* kbase = &Ks[krow * 256];
                const int kx = krow & 7;
#pragma unroll
                for (int km = 0; km < 8; ++km) {
                    const bf16x8 kf = *(const bf16x8*)(kbase + (((km * 4 + g) ^ kx) * 8));
                    sacc = __builtin_amdgcn_mfma_f32_16x16x32_bf16(kf, qf[km], sacc, 0, 0, 0);
                }
#pragma unroll
                for (int r = 0; r < 4; ++r) {
                    const int jgl = k0 + jb * 16 + g * 4 + r;
                    const bool ok = (jgl <= qrow) && (qrow - jgl < WINW) &&
                                    (Ams[jb * 16 + g * 4 + r] != 0);
                    const float val = ok ? sacc[r] : -1e30f;
                    okf[jb * 4 + r] = ok;
                    pv[jb * 4 + r] = val;
                    tmax = fmaxf(tmax, val);
                }
            }
            tmax = fmaxf(tmax, __shfl_xor(tmax, 16, 64));
            tmax = fmaxf(tmax, __shfl_xor(tmax, 32, 64));
            const float mnew = fmaxf(mrow, tmax);
            const float corr = __expf(mrow - mnew);
            float ps = 0.f;
#pragma unroll
            for (int i = 0; i < 8; ++i) {
                const float p = okf[i] ? __expf(pv[i] - mnew) : 0.f;
                pv[i] = p; ps += p;
            }
            ps += __shfl_xor(ps, 16, 64);
            ps += __shfl_xor(ps, 32, 64);
            lrow = lrow * corr + ps;
            mrow = mnew;

            // P -> per-wave LDS (bf16), packed pairs
            unsigned short* Pw = &Pl[w][0];
#pragma unroll
            for (int jb = 0; jb < 2; ++jb) {
                const unsigned int u0 = (unsigned int)f2bf(pv[jb * 4 + 0]) |
                                        ((unsigned int)f2bf(pv[jb * 4 + 1]) << 16);
                const unsigned int u1 = (unsigned int)f2bf(pv[jb * 4 + 2]) |
                                        ((unsigned int)f2bf(pv[jb * 4 + 3]) << 16);
                *(unsigned int*)&Pw[q15 * 40 + jb * 16 + g * 4]     = u0;
                *(unsigned int*)&Pw[q15 * 40 + jb * 16 + g * 4 + 2] = u1;
            }

            // rescale O accumulators (rows q = g*4+r; corr lives at lane q)
            if (__any(corr != 1.0f)) {
                const float c0 = __shfl(corr, g * 4 + 0, 64);
                const float c1 = __shfl(corr, g * 4 + 1, 64);
                const float c2 = __shfl(corr, g * 4 + 2, 64);
                const float c3 = __shfl(corr, g * 4 + 3, 64);
#pragma unroll
                for (int dm = 0; dm < 16; ++dm) {
                    oacc[dm][0] *= c0; oacc[dm][1] *= c1;
                    oacc[dm][2] *= c2; oacc[dm][3] *= c3;
                }
            }

            asm volatile("s_waitcnt lgkmcnt(0)" ::: "memory");
            const bf16x8 pa = *(const bf16x8*)&Pw[q15 * 40 + g * 8];
#pragma unroll
            for (int dm = 0; dm < 16; ++dm) {
                const int d = dm * 16 + q15;
                const bf16x8 vf = *(const bf16x8*)&Vts[d * 32 + ((g ^ (d & 3)) * 8)];
                oacc[dm] = __builtin_amdgcn_mfma_f32_16x16x32_bf16(pa, vf, oacc[dm], 0, 0, 0);
            }
        }
        __syncthreads();
    }

    // ---- epilogue: O[q][d] = acc/l ----
    float invl[4];
#pragma unroll
    for (int r = 0; r < 4; ++r) invl[r] = 1.0f / __shfl(lrow, g * 4 + r, 64);
#pragma unroll
    for (int dm = 0; dm < 16; ++dm) {
#pragma unroll
        for (int r = 0; r < 4; ++r) {
            const int qo = qb0 + w * 16 + g * 4 + r;
            O[((size_t)(b * SS + qo) * HH + h) * DD + dm * 16 + q15] = oacc[dm][r] * invl[r];
        }
    }
}

// ---------------------------------------------------------------------------
// Launch.  Workspace layout (64 MB total, aggressive reuse):
//   [ 0,32) MB qb fp32  : Q-proj out -> (dead after Q-norm) -> vb fp32 (first
//                         16 MB, V-proj out) -> attn O fp32 (32 MB)
//   [32,48) MB kb fp32  : K-proj out -> (dead after K-norm) -> Qb bf16
//   [48,56) MB Kb bf16
//   [56,64) MB Vt bf16  [b,kv,d,s]
// ---------------------------------------------------------------------------
extern "C" void kernel_launch(void* const* d_in, const int* in_sizes, int n_in,
                              void* d_out, int out_size, void* d_ws, size_t ws_size,
                              hipStream_t stream)
{
    (void)in_sizes; (void)n_in; (void)out_size; (void)ws_size;

    const float* X  = (const float*)d_in[0];
    const float* cs = (const float*)d_in[1];
    const float* sn = (const float*)d_in[2];
    const int*   am = (const int*)d_in[3];
    const float* Wq = (const float*)d_in[4];
    const float* Wk = (const float*)d_in[5];
    const float* Wv = (const float*)d_in[6];
    const float* Wo = (const float*)d_in[7];
    const float* qw = (const float*)d_in[8];
    const float* kw = (const float*)d_in[9];
    float* out = (float*)d_out;

    float* qb = (float*)d_ws;                                  // 8,388,608 f32
    float* kb = qb + (size_t)8388608;                          // 4,194,304 f32
    unsigned short* Qb = (unsigned short*)kb;                  // aliases kb
    unsigned short* Kb = (unsigned short*)(kb + (size_t)4194304);
    unsigned short* Vt = (unsigned short*)((char*)d_ws + (size_t)56 * 1024 * 1024);
    float* vb = qb;                                            // aliases dead qb
    float* Ob = qb;                                            // attn output

    const int M = BB * SS;   // 4096
    dim3 blk(256);

    // projections (fp32) + norms (bf16 out)
    gemm_f32<<<dim3((HH  * DD) / 128, M / 128), blk, 0, stream>>>(X, Wq, qb, M, HH  * DD, EE);
    gemm_f32<<<dim3((KVN * DD) / 128, M / 128), blk, 0, stream>>>(X, Wk, kb, M, KVN * DD, EE);
    rmsnorm_rope_bf16<KVN><<<dim3(BB * SS * KVN / 4), blk, 0, stream>>>(kb, Kb, kw, cs, sn, 1.0f);
    rmsnorm_rope_bf16<HH ><<<dim3(BB * SS * HH  / 4), blk, 0, stream>>>(qb, Qb, qw, cs, sn, 0.0625f);
    gemm_f32<<<dim3((KVN * DD) / 128, M / 128), blk, 0, stream>>>(X, Wv, vb, M, KVN * DD, EE);
    v_to_vt<<<dim3(SS / 64, DD / 64, BB * KVN), blk, 0, stream>>>(vb, Vt);

    // attention (bf16 MFMA), writes fp32 O into qb region
    attn_mfma<<<dim3(SS / 64, HH, BB), blk, 0, stream>>>(Qb, Kb, Vt, am, Ob);

    // output projection (fp32)
    gemm_f32<<<dim3(EE / 128, M / 128), blk, 0, stream>>>(Ob, Wo, out, M, EE, EE);
}

// Round 4
// 788.851 us; speedup vs baseline: 4.1539x; 2.2497x over previous
//
#include <hip/hip_runtime.h>
#include <math.h>

#define BB   2
#define SS   2048
#define EE   2048
#define HH   8
#define KVN  4
#define DD   256
#define WINW 1024
#define EPSV 1e-6f
#define NQKV 4096      // q(2048) | k(1024) | v(1024)

using bf16x8 = __attribute__((ext_vector_type(8))) __bf16;
using f32x4  = __attribute__((ext_vector_type(4))) float;

__device__ __forceinline__ unsigned short f2bf(float f) {
    union { float f; unsigned int u; } c; c.f = f;
    unsigned int u = c.u;
    unsigned int r = (u + 0x7FFFu + ((u >> 16) & 1u)) >> 16;   // RTNE
    return (unsigned short)r;
}
__device__ __forceinline__ float bf2f(unsigned short u) {
    union { unsigned int u; float f; } c; c.u = ((unsigned int)u) << 16;
    return c.f;
}

#if defined(__has_builtin)
#if __has_builtin(__builtin_amdgcn_global_load_lds)
#define HAVE_GLL 1
#endif
#endif

#ifdef HAVE_GLL
#define GLOAD_LDS16(gp, sp) __builtin_amdgcn_global_load_lds( \
    (const __attribute__((address_space(1))) unsigned int*)(gp), \
    (__attribute__((address_space(3))) unsigned int*)(sp), 16, 0, 0)
#endif

// ---------------------------------------------------------------------------
// fp32 GEMM (94% of fp32 vector peak measured) — used only for Wo now.
// ---------------------------------------------------------------------------
__global__ __launch_bounds__(256)
void gemm_f32(const float* __restrict__ A, const float* __restrict__ Bw,
              float* __restrict__ C, int M, int N, int K)
{
    __shared__ float As[8][128];
    __shared__ float Bs[8][128];
    const int t    = threadIdx.x;
    const int bm   = blockIdx.y * 128;
    const int bn   = blockIdx.x * 128;
    const int tx   = t & 15;
    const int ty   = t >> 4;
    const int arow = t >> 1;
    const int ak   = (t & 1) * 4;
    const int brow = t >> 5;
    const int bcol = (t & 31) * 4;
    const float* Ap = A  + (size_t)(bm + arow) * K + ak;
    const float* Bp = Bw + (size_t)brow * N + bn + bcol;

    float acc[8][8];
#pragma unroll
    for (int i = 0; i < 8; ++i)
#pragma unroll
        for (int j = 0; j < 8; ++j) acc[i][j] = 0.f;

    for (int k0 = 0; k0 < K; k0 += 8) {
        const float4 av = *(const float4*)(Ap + k0);
        const float4 bv = *(const float4*)(Bp + (size_t)k0 * N);
        __syncthreads();
        As[ak + 0][arow] = av.x;
        As[ak + 1][arow] = av.y;
        As[ak + 2][arow] = av.z;
        As[ak + 3][arow] = av.w;
        *(float4*)&Bs[brow][bcol] = bv;
        __syncthreads();
#pragma unroll
        for (int kk = 0; kk < 8; ++kk) {
            float ar[8], br[8];
            *(float4*)&ar[0] = *(const float4*)&As[kk][ty * 8];
            *(float4*)&ar[4] = *(const float4*)&As[kk][ty * 8 + 4];
            *(float4*)&br[0] = *(const float4*)&Bs[kk][tx * 4];
            *(float4*)&br[4] = *(const float4*)&Bs[kk][tx * 4 + 64];
#pragma unroll
            for (int i = 0; i < 8; ++i)
#pragma unroll
                for (int j = 0; j < 8; ++j)
                    acc[i][j] = fmaf(ar[i], br[j], acc[i][j]);
        }
    }
#pragma unroll
    for (int i = 0; i < 8; ++i) {
        float* Crow = C + (size_t)(bm + ty * 8 + i) * N + bn;
        *(float4*)(Crow + tx * 4)      = make_float4(acc[i][0], acc[i][1], acc[i][2], acc[i][3]);
        *(float4*)(Crow + 64 + tx * 4) = make_float4(acc[i][4], acc[i][5], acc[i][6], acc[i][7]);
    }
}

// ---------------------------------------------------------------------------
// X fp32 -> bf16 (elementwise, 8 per thread)
// ---------------------------------------------------------------------------
__global__ __launch_bounds__(256)
void conv_x(const float* __restrict__ X, unsigned short* __restrict__ Xb)
{
    const size_t i = ((size_t)blockIdx.x * 256 + threadIdx.x) * 8;
    const float4 a = *(const float4*)(X + i);
    const float4 b = *(const float4*)(X + i + 4);
    ushort4 lo, hi;
    lo.x = f2bf(a.x); lo.y = f2bf(a.y); lo.z = f2bf(a.z); lo.w = f2bf(a.w);
    hi.x = f2bf(b.x); hi.y = f2bf(b.y); hi.z = f2bf(b.z); hi.w = f2bf(b.w);
    *(ushort4*)(Xb + i)     = lo;
    *(ushort4*)(Xb + i + 4) = hi;
}

// ---------------------------------------------------------------------------
// Weight fuse+transpose+convert: Wq[K,2048],Wk[K,1024],Wv[K,1024] fp32 ->
// Wt bf16 [N=4096][K=2048] (row n = output column, B^T layout for the GEMM).
// 64x64 tiles through LDS.
// ---------------------------------------------------------------------------
__global__ __launch_bounds__(256)
void conv_wt(const float* __restrict__ Wq, const float* __restrict__ Wk,
             const float* __restrict__ Wv, unsigned short* __restrict__ Wt)
{
    __shared__ unsigned short Lt[64][72];
    const int k0 = blockIdx.x * 64, n0 = blockIdx.y * 64;
    const int t = threadIdx.x;
    const float* src; int ld, nc;
    if (n0 < 2048)      { src = Wq; ld = 2048; nc = n0; }
    else if (n0 < 3072) { src = Wk; ld = 1024; nc = n0 - 2048; }
    else                { src = Wv; ld = 1024; nc = n0 - 3072; }

#pragma unroll
    for (int p = 0; p < 4; ++p) {
        const int kr = p * 16 + (t >> 4);
        const float4 fv = *(const float4*)(src + (size_t)(k0 + kr) * ld + nc + (t & 15) * 4);
        Lt[kr][(t & 15) * 4 + 0] = f2bf(fv.x);
        Lt[kr][(t & 15) * 4 + 1] = f2bf(fv.y);
        Lt[kr][(t & 15) * 4 + 2] = f2bf(fv.z);
        Lt[kr][(t & 15) * 4 + 3] = f2bf(fv.w);
    }
    __syncthreads();
    const int n = t >> 2, kseg = t & 3;
    unsigned short tmp[16];
#pragma unroll
    for (int j = 0; j < 16; ++j) tmp[j] = Lt[kseg * 16 + j][n];
    unsigned short* dst = Wt + (size_t)(n0 + n) * EE + k0 + kseg * 16;
    *(uint4*)(dst)     = *(uint4*)&tmp[0];
    *(uint4*)(dst + 8) = *(uint4*)&tmp[8];
}

// ---------------------------------------------------------------------------
// bf16 MFMA GEMM (m97 structure): C[M,N] bf16 = A[M,K] bf16 @ Bt[N,K]^T.
// 128x128 tile, BK=32, 4 waves (2x2 of 64x64), global_load_lds width-16
// staging into linear LDS, 16 MFMAs (16x16x32) per K-tile.
// ---------------------------------------------------------------------------
__global__ __launch_bounds__(256)
void gemm_bf16(const unsigned short* __restrict__ A,
               const unsigned short* __restrict__ Bt,
               unsigned short* __restrict__ C, int M, int N, int K)
{
    __shared__ unsigned short As[128 * 32];
    __shared__ unsigned short Bs[128 * 32];
    const int t = threadIdx.x;
    const int w = t >> 6;
    const int l = t & 63;
    const int bm = blockIdx.y * 128, bn = blockIdx.x * 128;
    const int wr = w >> 1, wc = w & 1;
    const int l16 = l & 15, lq = l >> 4;

    const int srow = t >> 2;            // 0..63
    const int sk8  = (t & 3) * 8;       // bf16 element offset within row
    const unsigned short* Ag = A  + (size_t)(bm + srow) * K + sk8;
    const unsigned short* Bg = Bt + (size_t)(bn + srow) * K + sk8;

    f32x4 acc[4][4];
#pragma unroll
    for (int i = 0; i < 4; ++i)
#pragma unroll
        for (int j = 0; j < 4; ++j) acc[i][j] = (f32x4){0.f, 0.f, 0.f, 0.f};

    for (int k0 = 0; k0 < K; k0 += 32) {
        __syncthreads();                 // previous tile's LDS reads done
#ifdef HAVE_GLL
        GLOAD_LDS16(Ag + k0,            &As[t * 8]);
        GLOAD_LDS16(Ag + k0 + 64 * K,   &As[2048 + t * 8]);
        GLOAD_LDS16(Bg + k0,            &Bs[t * 8]);
        GLOAD_LDS16(Bg + k0 + 64 * K,   &Bs[2048 + t * 8]);
#else
        const uint4 a0 = *(const uint4*)(Ag + k0);
        const uint4 a1 = *(const uint4*)(Ag + k0 + 64 * K);
        const uint4 b0 = *(const uint4*)(Bg + k0);
        const uint4 b1 = *(const uint4*)(Bg + k0 + 64 * K);
        *(uint4*)&As[t * 8]        = a0;
        *(uint4*)&As[2048 + t * 8] = a1;
        *(uint4*)&Bs[t * 8]        = b0;
        *(uint4*)&Bs[2048 + t * 8] = b1;
#endif
        __syncthreads();                 // staging visible (vmcnt drained)

        bf16x8 af[4], bf[4];
#pragma unroll
        for (int i = 0; i < 4; ++i)
            af[i] = *(const bf16x8*)&As[(wr * 64 + i * 16 + l16) * 32 + lq * 8];
#pragma unroll
        for (int j = 0; j < 4; ++j)
            bf[j] = *(const bf16x8*)&Bs[(wc * 64 + j * 16 + l16) * 32 + lq * 8];
#pragma unroll
        for (int i = 0; i < 4; ++i)
#pragma unroll
            for (int j = 0; j < 4; ++j)
                acc[i][j] = __builtin_amdgcn_mfma_f32_16x16x32_bf16(af[i], bf[j], acc[i][j], 0, 0, 0);
    }

#pragma unroll
    for (int i = 0; i < 4; ++i)
#pragma unroll
        for (int j = 0; j < 4; ++j)
#pragma unroll
            for (int r = 0; r < 4; ++r)
                C[(size_t)(bm + wr * 64 + i * 16 + lq * 4 + r) * N +
                  (bn + wc * 64 + j * 16 + l16)] = f2bf(acc[i][j][r]);
}

// ---------------------------------------------------------------------------
// Fused RMSNorm (scale=1+w) + RoPE; reads bf16 from the packed qkv buffer,
// writes bf16 [b,s,nh,d]. COLOFF selects the q or k slice.
// ---------------------------------------------------------------------------
template <int NH, int COLOFF>
__global__ __launch_bounds__(256)
void rmsnorm_rope_qkv(const unsigned short* __restrict__ qkv,
                      unsigned short* __restrict__ out,
                      const float* __restrict__ w,
                      const float* __restrict__ cs, const float* __restrict__ sn,
                      float scale)
{
    const int wv   = threadIdx.x >> 6;
    const int lane = threadIdx.x & 63;
    const int row  = blockIdx.x * 4 + wv;     // m*NH + hh
    const int m    = row / NH;
    const int hh   = row - m * NH;
    const unsigned short* xr = qkv + (size_t)m * NQKV + COLOFF + hh * DD;

    const ushort4 u4 = ((const ushort4*)xr)[lane];
    float4 xv;
    xv.x = bf2f(u4.x); xv.y = bf2f(u4.y); xv.z = bf2f(u4.z); xv.w = bf2f(u4.w);
    float ss = xv.x * xv.x + xv.y * xv.y + xv.z * xv.z + xv.w * xv.w;
#pragma unroll
    for (int d = 1; d < 64; d <<= 1) ss += __shfl_xor(ss, d, 64);
    const float inv = 1.0f / sqrtf(ss * (1.0f / (float)DD) + EPSV);

    const float4 w4 = ((const float4*)w)[lane];
    float4 y;
    y.x = xv.x * inv * (1.f + w4.x);
    y.y = xv.y * inv * (1.f + w4.y);
    y.z = xv.z * inv * (1.f + w4.z);
    y.w = xv.w * inv * (1.f + w4.w);

    __shared__ float4 buf[4][64];
    buf[wv][lane] = y;
    __syncthreads();
    const float4 r0 = buf[wv][(lane < 32) ? (lane + 32) : (lane - 32)];
    float4 rot;
    if (lane < 32) { rot.x = -r0.x; rot.y = -r0.y; rot.z = -r0.z; rot.w = -r0.w; }
    else           { rot = r0; }

    const float4 c4 = ((const float4*)(cs + (size_t)m * DD))[lane];
    const float4 s4 = ((const float4*)(sn + (size_t)m * DD))[lane];
    ushort4 o4;
    o4.x = f2bf((y.x * c4.x + rot.x * s4.x) * scale);
    o4.y = f2bf((y.y * c4.y + rot.y * s4.y) * scale);
    o4.z = f2bf((y.z * c4.z + rot.z * s4.z) * scale);
    o4.w = f2bf((y.w * c4.w + rot.w * s4.w) * scale);
    ((ushort4*)(out + (size_t)row * DD))[lane] = o4;
}

// ---------------------------------------------------------------------------
// V transpose: qkv bf16 v-slice [m][3072 + kv*256 + d] -> Vt bf16 [b,kv,d,s].
// ---------------------------------------------------------------------------
__global__ __launch_bounds__(256)
void v_to_vt(const unsigned short* __restrict__ qkv, unsigned short* __restrict__ Vt)
{
    __shared__ unsigned short Lt[64][72];
    const int s0 = blockIdx.x * 64, d0 = blockIdx.y * 64;
    const int bkv = blockIdx.z;               // b*KVN + kv
    const int b = bkv >> 2, kv = bkv & 3;
    const int t = threadIdx.x;

    {   // load bf16 rows [s][d]
        const int s = t >> 2, seg = t & 3;
        const unsigned short* src = qkv + (size_t)(b * SS + s0 + s) * NQKV +
                                    3072 + kv * DD + d0 + seg * 16;
        *(uint4*)&Lt[s][seg * 16]     = *(const uint4*)(src);
        *(uint4*)&Lt[s][seg * 16 + 8] = *(const uint4*)(src + 8);
    }
    __syncthreads();
    {   // write [d][s]
        const int d = t >> 2, sseg = t & 3;
        unsigned short tmp[16];
#pragma unroll
        for (int j = 0; j < 16; ++j) tmp[j] = Lt[sseg * 16 + j][d];
        unsigned short* dst = Vt + ((size_t)bkv * DD + d0 + d) * SS + s0 + sseg * 16;
        *(uint4*)(dst)     = *(uint4*)&tmp[0];
        *(uint4*)(dst + 8) = *(uint4*)&tmp[8];
    }
}

// ---------------------------------------------------------------------------
// bf16 MFMA flash attention (unchanged from R2 — verified).
// ---------------------------------------------------------------------------
__global__ __launch_bounds__(256, 2)
void attn_mfma(const unsigned short* __restrict__ Qb,
               const unsigned short* __restrict__ Kb,
               const unsigned short* __restrict__ Vt,
               const int* __restrict__ am, float* __restrict__ O)
{
    __shared__ unsigned short Ks[32 * 256];    // [j][d], chunk-swizzled
    __shared__ unsigned short Vts[256 * 32];   // [d][j], chunk-swizzled
    __shared__ unsigned short Pl[4][16 * 40];  // per-wave P, row pad 40
    __shared__ int Ams[32];

    const int t = threadIdx.x, w = t >> 6, l = t & 63;
    const int g = l >> 4, q15 = l & 15;
    const int qb0 = blockIdx.x * 64, h = blockIdx.y, b = blockIdx.z;
    const int kvh = h >> 1;
    const int qrow = qb0 + w * 16 + q15;

    bf16x8 qf[8];
    {
        const unsigned short* qp = Qb + ((size_t)(b * SS + qrow) * HH + h) * DD + g * 8;
#pragma unroll
        for (int km = 0; km < 8; ++km) qf[km] = *(const bf16x8*)(qp + km * 32);
    }

    f32x4 oacc[16];
#pragma unroll
    for (int i = 0; i < 16; ++i) oacc[i] = (f32x4){0.f, 0.f, 0.f, 0.f};
    float mrow = -1e30f, lrow = 0.f;

    const int qlo = qb0 + w * 16, qhi = qlo + 15;
    int kstart = qb0 - 1024; if (kstart < 0) kstart = 0;
    const int kend = qb0 + 32;

    const int sj = t >> 3, sc = t & 7;

    for (int k0 = kstart; k0 <= kend; k0 += 32) {
        {
            const unsigned short* kp = Kb + ((size_t)(b * SS + k0 + sj) * KVN + kvh) * DD + sc * 32;
#pragma unroll
            for (int i = 0; i < 4; ++i) {
                const int cc = sc * 4 + i;
                *(uint4*)&Ks[sj * 256 + ((cc ^ (sj & 7)) * 8)] = *(const uint4*)(kp + i * 8);
            }
#pragma unroll
            for (int it = 0; it < 4; ++it) {
                const int d = it * 64 + (t >> 2), c = t & 3;
                const unsigned short* vp = Vt + ((size_t)(b * KVN + kvh) * DD + d) * SS + k0 + c * 8;
                *(uint4*)&Vts[d * 32 + ((c ^ (d & 3)) * 8)] = *(const uint4*)vp;
            }
            if (t < 32) Ams[t] = am[b * SS + k0 + t];
        }
        __syncthreads();

        if (k0 <= qhi && k0 + 31 >= qlo - (WINW - 1)) {
            float pv[8];
            int   okf[8];
            float tmax = -1e30f;
#pragma unroll
            for (int jb = 0; jb < 2; ++jb) {
                f32x4 sacc = (f32x4){0.f, 0.f, 0.f, 0.f};
                const int krow = jb * 16 + q15;
                const unsigned short* kbase = &Ks[krow * 256];
                const int kx = krow & 7;
#pragma unroll
                for (int km = 0; km < 8; ++km) {
                    const bf16x8 kf = *(const bf16x8*)(kbase + (((km * 4 + g) ^ kx) * 8));
                    sacc = __builtin_amdgcn_mfma_f32_16x16x32_bf16(kf, qf[km], sacc, 0, 0, 0);
                }
#pragma unroll
                for (int r = 0; r < 4; ++r) {
                    const int jgl = k0 + jb * 16 + g * 4 + r;
                    const bool ok = (jgl <= qrow) && (qrow - jgl < WINW) &&
                                    (Ams[jb * 16 + g * 4 + r] != 0);
                    const float val = ok ? sacc[r] : -1e30f;
                    okf[jb * 4 + r] = ok;
                    pv[jb * 4 + r] = val;
                    tmax = fmaxf(tmax, val);
                }
            }
            tmax = fmaxf(tmax, __shfl_xor(tmax, 16, 64));
            tmax = fmaxf(tmax, __shfl_xor(tmax, 32, 64));
            const float mnew = fmaxf(mrow, tmax);
            const float corr = __expf(mrow - mnew);
            float ps = 0.f;
#pragma unroll
            for (int i = 0; i < 8; ++i) {
                const float p = okf[i] ? __expf(pv[i] - mnew) : 0.f;
                pv[i] = p; ps += p;
            }
            ps += __shfl_xor(ps, 16, 64);
            ps += __shfl_xor(ps, 32, 64);
            lrow = lrow * corr + ps;
            mrow = mnew;

            unsigned short* Pw = &Pl[w][0];
#pragma unroll
            for (int jb = 0; jb < 2; ++jb) {
                const unsigned int u0 = (unsigned int)f2bf(pv[jb * 4 + 0]) |
                                        ((unsigned int)f2bf(pv[jb * 4 + 1]) << 16);
                const unsigned int u1 = (unsigned int)f2bf(pv[jb * 4 + 2]) |
                                        ((unsigned int)f2bf(pv[jb * 4 + 3]) << 16);
                *(unsigned int*)&Pw[q15 * 40 + jb * 16 + g * 4]     = u0;
                *(unsigned int*)&Pw[q15 * 40 + jb * 16 + g * 4 + 2] = u1;
            }

            if (__any(corr != 1.0f)) {
                const float c0 = __shfl(corr, g * 4 + 0, 64);
                const float c1 = __shfl(corr, g * 4 + 1, 64);
                const float c2 = __shfl(corr, g * 4 + 2, 64);
                const float c3 = __shfl(corr, g * 4 + 3, 64);
#pragma unroll
                for (int dm = 0; dm < 16; ++dm) {
                    oacc[dm][0] *= c0; oacc[dm][1] *= c1;
                    oacc[dm][2] *= c2; oacc[dm][3] *= c3;
                }
            }

            asm volatile("s_waitcnt lgkmcnt(0)" ::: "memory");
            const bf16x8 pa = *(const bf16x8*)&Pw[q15 * 40 + g * 8];
#pragma unroll
            for (int dm = 0; dm < 16; ++dm) {
                const int d = dm * 16 + q15;
                const bf16x8 vf = *(const bf16x8*)&Vts[d * 32 + ((g ^ (d & 3)) * 8)];
                oacc[dm] = __builtin_amdgcn_mfma_f32_16x16x32_bf16(pa, vf, oacc[dm], 0, 0, 0);
            }
        }
        __syncthreads();
    }

    float invl[4];
#pragma unroll
    for (int r = 0; r < 4; ++r) invl[r] = 1.0f / __shfl(lrow, g * 4 + r, 64);
#pragma unroll
    for (int dm = 0; dm < 16; ++dm) {
#pragma unroll
        for (int r = 0; r < 4; ++r) {
            const int qo = qb0 + w * 16 + g * 4 + r;
            O[((size_t)(b * SS + qo) * HH + h) * DD + dm * 16 + q15] = oacc[dm][r] * invl[r];
        }
    }
}

// ---------------------------------------------------------------------------
// Launch. Workspace (64 MiB, phase-reuse):
//   [ 0,16) MiB  Xb bf16            -> Qb bf16 (after GEMM)
//   [16,32) MiB  Wt bf16 [4096][2048] -> Kb bf16 [16,24) + Vt bf16 [24,32)
//   [32,64) MiB  qkv bf16 [4096][4096] -> O fp32 (after norms/v_to_vt)
// ---------------------------------------------------------------------------
extern "C" void kernel_launch(void* const* d_in, const int* in_sizes, int n_in,
                              void* d_out, int out_size, void* d_ws, size_t ws_size,
                              hipStream_t stream)
{
    (void)in_sizes; (void)n_in; (void)out_size; (void)ws_size;

    const float* X  = (const float*)d_in[0];
    const float* cs = (const float*)d_in[1];
    const float* sn = (const float*)d_in[2];
    const int*   am = (const int*)d_in[3];
    const float* Wq = (const float*)d_in[4];
    const float* Wk = (const float*)d_in[5];
    const float* Wv = (const float*)d_in[6];
    const float* Wo = (const float*)d_in[7];
    const float* qw = (const float*)d_in[8];
    const float* kw = (const float*)d_in[9];
    float* out = (float*)d_out;

    char* ws = (char*)d_ws;
    unsigned short* Xb  = (unsigned short*)(ws);                            // 16 MiB
    unsigned short* Qb  = (unsigned short*)(ws);                            // aliases Xb
    unsigned short* Wt  = (unsigned short*)(ws + (size_t)16 * 1024 * 1024); // 16 MiB
    unsigned short* Kb  = (unsigned short*)(ws + (size_t)16 * 1024 * 1024); // aliases Wt
    unsigned short* Vt  = (unsigned short*)(ws + (size_t)24 * 1024 * 1024);
    unsigned short* qkv = (unsigned short*)(ws + (size_t)32 * 1024 * 1024); // 32 MiB
    float*          Ob  = (float*)        (ws + (size_t)32 * 1024 * 1024);  // aliases qkv

    const int M = BB * SS;   // 4096
    dim3 blk(256);

    // bf16 conversions
    conv_x <<<dim3((M * EE) / (256 * 8)), blk, 0, stream>>>(X, Xb);
    conv_wt<<<dim3(EE / 64, NQKV / 64), blk, 0, stream>>>(Wq, Wk, Wv, Wt);

    // fused QKV projection (bf16 MFMA)
    gemm_bf16<<<dim3(NQKV / 128, M / 128), blk, 0, stream>>>(Xb, Wt, qkv, M, NQKV, EE);

    // norms (read qkv slices, write packed bf16 buffers); q-scale folded
    rmsnorm_rope_qkv<KVN, 2048><<<dim3(M * KVN / 4), blk, 0, stream>>>(qkv, Kb, kw, cs, sn, 1.0f);
    rmsnorm_rope_qkv<HH, 0>    <<<dim3(M * HH  / 4), blk, 0, stream>>>(qkv, Qb, qw, cs, sn, 0.0625f);
    v_to_vt<<<dim3(SS / 64, DD / 64, BB * KVN), blk, 0, stream>>>(qkv, Vt);

    // attention (bf16 MFMA) -> fp32 O over the dead qkv region
    attn_mfma<<<dim3(SS / 64, HH, BB), blk, 0, stream>>>(Qb, Kb, Vt, am, Ob);

    // output projection (fp32, precision hedge)
    gemm_f32<<<dim3(EE / 128, M / 128), blk, 0, stream>>>(Ob, Wo, out, M, EE, EE);
}

// Round 6
// 450.921 us; speedup vs baseline: 7.2670x; 1.7494x over previous
//
#include <hip/hip_runtime.h>
#include <math.h>

#define BB   2
#define SS   2048
#define EE   2048
#define HH   8
#define KVN  4
#define DD   256
#define WINW 1024
#define EPSV 1e-6f
#define NQKV 4096      // q(2048) | k(1024) | v(1024)

using bf16x8 = __attribute__((ext_vector_type(8))) __bf16;
using f32x4  = __attribute__((ext_vector_type(4))) float;

__device__ __forceinline__ unsigned short f2bf(float f) {
    union { float f; unsigned int u; } c; c.f = f;
    unsigned int u = c.u;
    unsigned int r = (u + 0x7FFFu + ((u >> 16) & 1u)) >> 16;   // RTNE
    return (unsigned short)r;
}
__device__ __forceinline__ float bf2f(unsigned short u) {
    union { unsigned int u; float f; } c; c.u = ((unsigned int)u) << 16;
    return c.f;
}

#if defined(__has_builtin)
#if __has_builtin(__builtin_amdgcn_global_load_lds)
#define HAVE_GLL 1
#endif
#endif

#ifdef HAVE_GLL
#define GLOAD_LDS16(gp, sp) __builtin_amdgcn_global_load_lds( \
    (const __attribute__((address_space(1))) unsigned int*)(gp), \
    (__attribute__((address_space(3))) unsigned int*)(sp), 16, 0, 0)
#endif

// ---------------------------------------------------------------------------
// X fp32 -> bf16 (elementwise, 8 per thread)
// ---------------------------------------------------------------------------
__global__ __launch_bounds__(256)
void conv_x(const float* __restrict__ X, unsigned short* __restrict__ Xb)
{
    const size_t i = ((size_t)blockIdx.x * 256 + threadIdx.x) * 8;
    const float4 a = *(const float4*)(X + i);
    const float4 b = *(const float4*)(X + i + 4);
    ushort4 lo, hi;
    lo.x = f2bf(a.x); lo.y = f2bf(a.y); lo.z = f2bf(a.z); lo.w = f2bf(a.w);
    hi.x = f2bf(b.x); hi.y = f2bf(b.y); hi.z = f2bf(b.z); hi.w = f2bf(b.w);
    *(ushort4*)(Xb + i)     = lo;
    *(ushort4*)(Xb + i + 4) = hi;
}

// ---------------------------------------------------------------------------
// Weight fuse+transpose+convert: Wq[K,2048],Wk[K,1024],Wv[K,1024] fp32 ->
// Wt bf16 [N=4096][K=2048] (B^T layout). 64x64 tiles through LDS.
// ---------------------------------------------------------------------------
__global__ __launch_bounds__(256)
void conv_wt(const float* __restrict__ Wq, const float* __restrict__ Wk,
             const float* __restrict__ Wv, unsigned short* __restrict__ Wt)
{
    __shared__ unsigned short Lt[64][72];
    const int k0 = blockIdx.x * 64, n0 = blockIdx.y * 64;
    const int t = threadIdx.x;
    const float* src; int ld, nc;
    if (n0 < 2048)      { src = Wq; ld = 2048; nc = n0; }
    else if (n0 < 3072) { src = Wk; ld = 1024; nc = n0 - 2048; }
    else                { src = Wv; ld = 1024; nc = n0 - 3072; }

#pragma unroll
    for (int p = 0; p < 4; ++p) {
        const int kr = p * 16 + (t >> 4);
        const float4 fv = *(const float4*)(src + (size_t)(k0 + kr) * ld + nc + (t & 15) * 4);
        Lt[kr][(t & 15) * 4 + 0] = f2bf(fv.x);
        Lt[kr][(t & 15) * 4 + 1] = f2bf(fv.y);
        Lt[kr][(t & 15) * 4 + 2] = f2bf(fv.z);
        Lt[kr][(t & 15) * 4 + 3] = f2bf(fv.w);
    }
    __syncthreads();
    const int n = t >> 2, kseg = t & 3;
    unsigned short tmp[16];
#pragma unroll
    for (int j = 0; j < 16; ++j) tmp[j] = Lt[kseg * 16 + j][n];
    unsigned short* dst = Wt + (size_t)(n0 + n) * EE + k0 + kseg * 16;
    *(uint4*)(dst)     = *(uint4*)&tmp[0];
    *(uint4*)(dst + 8) = *(uint4*)&tmp[8];
}

// ---------------------------------------------------------------------------
// Wo transpose+convert: Wo fp32 [K=2048][N=2048] -> Wot bf16 [N][K].
// ---------------------------------------------------------------------------
__global__ __launch_bounds__(256)
void conv_wo(const float* __restrict__ W, unsigned short* __restrict__ Wot)
{
    __shared__ unsigned short Lt[64][72];
    const int k0 = blockIdx.x * 64, n0 = blockIdx.y * 64;
    const int t = threadIdx.x;

#pragma unroll
    for (int p = 0; p < 4; ++p) {
        const int kr = p * 16 + (t >> 4);
        const float4 fv = *(const float4*)(W + (size_t)(k0 + kr) * 2048 + n0 + (t & 15) * 4);
        Lt[kr][(t & 15) * 4 + 0] = f2bf(fv.x);
        Lt[kr][(t & 15) * 4 + 1] = f2bf(fv.y);
        Lt[kr][(t & 15) * 4 + 2] = f2bf(fv.z);
        Lt[kr][(t & 15) * 4 + 3] = f2bf(fv.w);
    }
    __syncthreads();
    const int n = t >> 2, kseg = t & 3;
    unsigned short tmp[16];
#pragma unroll
    for (int j = 0; j < 16; ++j) tmp[j] = Lt[kseg * 16 + j][n];
    unsigned short* dst = Wot + (size_t)(n0 + n) * 2048 + k0 + kseg * 16;
    *(uint4*)(dst)     = *(uint4*)&tmp[0];
    *(uint4*)(dst + 8) = *(uint4*)&tmp[8];
}

// ---------------------------------------------------------------------------
// bf16 MFMA GEMM (m97 structure): C[M,N] = A[M,K] bf16 @ Bt[N,K]^T.
// 128x128 tile, BK=32, 4 waves (2x2 of 64x64), global_load_lds width-16.
// F32OUT selects fp32 (d_out) vs bf16 (intermediate) C stores.
// ---------------------------------------------------------------------------
template <bool F32OUT>
__global__ __launch_bounds__(256)
void gemm_bf16(const unsigned short* __restrict__ A,
               const unsigned short* __restrict__ Bt,
               void* __restrict__ Cv, int M, int N, int K)
{
    __shared__ unsigned short As[128 * 32];
    __shared__ unsigned short Bs[128 * 32];
    const int t = threadIdx.x;
    const int w = t >> 6;
    const int l = t & 63;
    const int bm = blockIdx.y * 128, bn = blockIdx.x * 128;
    const int wr = w >> 1, wc = w & 1;
    const int l16 = l & 15, lq = l >> 4;

    const int srow = t >> 2;
    const int sk8  = (t & 3) * 8;
    const unsigned short* Ag = A  + (size_t)(bm + srow) * K + sk8;
    const unsigned short* Bg = Bt + (size_t)(bn + srow) * K + sk8;

    f32x4 acc[4][4];
#pragma unroll
    for (int i = 0; i < 4; ++i)
#pragma unroll
        for (int j = 0; j < 4; ++j) acc[i][j] = (f32x4){0.f, 0.f, 0.f, 0.f};

    for (int k0 = 0; k0 < K; k0 += 32) {
        __syncthreads();
#ifdef HAVE_GLL
        GLOAD_LDS16(Ag + k0,            &As[t * 8]);
        GLOAD_LDS16(Ag + k0 + 64 * K,   &As[2048 + t * 8]);
        GLOAD_LDS16(Bg + k0,            &Bs[t * 8]);
        GLOAD_LDS16(Bg + k0 + 64 * K,   &Bs[2048 + t * 8]);
#else
        const uint4 a0 = *(const uint4*)(Ag + k0);
        const uint4 a1 = *(const uint4*)(Ag + k0 + 64 * K);
        const uint4 b0 = *(const uint4*)(Bg + k0);
        const uint4 b1 = *(const uint4*)(Bg + k0 + 64 * K);
        *(uint4*)&As[t * 8]        = a0;
        *(uint4*)&As[2048 + t * 8] = a1;
        *(uint4*)&Bs[t * 8]        = b0;
        *(uint4*)&Bs[2048 + t * 8] = b1;
#endif
        __syncthreads();

        bf16x8 af[4], bf[4];
#pragma unroll
        for (int i = 0; i < 4; ++i)
            af[i] = *(const bf16x8*)&As[(wr * 64 + i * 16 + l16) * 32 + lq * 8];
#pragma unroll
        for (int j = 0; j < 4; ++j)
            bf[j] = *(const bf16x8*)&Bs[(wc * 64 + j * 16 + l16) * 32 + lq * 8];
#pragma unroll
        for (int i = 0; i < 4; ++i)
#pragma unroll
            for (int j = 0; j < 4; ++j)
                acc[i][j] = __builtin_amdgcn_mfma_f32_16x16x32_bf16(af[i], bf[j], acc[i][j], 0, 0, 0);
    }

#pragma unroll
    for (int i = 0; i < 4; ++i)
#pragma unroll
        for (int j = 0; j < 4; ++j)
#pragma unroll
            for (int r = 0; r < 4; ++r) {
                const size_t idx = (size_t)(bm + wr * 64 + i * 16 + lq * 4 + r) * N +
                                   (bn + wc * 64 + j * 16 + l16);
                if constexpr (F32OUT) ((float*)Cv)[idx] = acc[i][j][r];
                else ((unsigned short*)Cv)[idx] = f2bf(acc[i][j][r]);
            }
}

// ---------------------------------------------------------------------------
// Fused RMSNorm (scale=1+w) + RoPE; reads bf16 qkv slice, writes bf16.
// ---------------------------------------------------------------------------
template <int NH, int COLOFF>
__global__ __launch_bounds__(256)
void rmsnorm_rope_qkv(const unsigned short* __restrict__ qkv,
                      unsigned short* __restrict__ out,
                      const float* __restrict__ w,
                      const float* __restrict__ cs, const float* __restrict__ sn,
                      float scale)
{
    const int wv   = threadIdx.x >> 6;
    const int lane = threadIdx.x & 63;
    const int row  = blockIdx.x * 4 + wv;     // m*NH + hh
    const int m    = row / NH;
    const int hh   = row - m * NH;
    const unsigned short* xr = qkv + (size_t)m * NQKV + COLOFF + hh * DD;

    const ushort4 u4 = ((const ushort4*)xr)[lane];
    float4 xv;
    xv.x = bf2f(u4.x); xv.y = bf2f(u4.y); xv.z = bf2f(u4.z); xv.w = bf2f(u4.w);
    float ss = xv.x * xv.x + xv.y * xv.y + xv.z * xv.z + xv.w * xv.w;
#pragma unroll
    for (int d = 1; d < 64; d <<= 1) ss += __shfl_xor(ss, d, 64);
    const float inv = 1.0f / sqrtf(ss * (1.0f / (float)DD) + EPSV);

    const float4 w4 = ((const float4*)w)[lane];
    float4 y;
    y.x = xv.x * inv * (1.f + w4.x);
    y.y = xv.y * inv * (1.f + w4.y);
    y.z = xv.z * inv * (1.f + w4.z);
    y.w = xv.w * inv * (1.f + w4.w);

    __shared__ float4 buf[4][64];
    buf[wv][lane] = y;
    __syncthreads();
    const float4 r0 = buf[wv][(lane < 32) ? (lane + 32) : (lane - 32)];
    float4 rot;
    if (lane < 32) { rot.x = -r0.x; rot.y = -r0.y; rot.z = -r0.z; rot.w = -r0.w; }
    else           { rot = r0; }

    const float4 c4 = ((const float4*)(cs + (size_t)m * DD))[lane];
    const float4 s4 = ((const float4*)(sn + (size_t)m * DD))[lane];
    ushort4 o4;
    o4.x = f2bf((y.x * c4.x + rot.x * s4.x) * scale);
    o4.y = f2bf((y.y * c4.y + rot.y * s4.y) * scale);
    o4.z = f2bf((y.z * c4.z + rot.z * s4.z) * scale);
    o4.w = f2bf((y.w * c4.w + rot.w * s4.w) * scale);
    ((ushort4*)(out + (size_t)row * DD))[lane] = o4;
}

// ---------------------------------------------------------------------------
// V transpose: qkv bf16 v-slice -> Vt bf16 [b,kv,d,s].
// ---------------------------------------------------------------------------
__global__ __launch_bounds__(256)
void v_to_vt(const unsigned short* __restrict__ qkv, unsigned short* __restrict__ Vt)
{
    __shared__ unsigned short Lt[64][72];
    const int s0 = blockIdx.x * 64, d0 = blockIdx.y * 64;
    const int bkv = blockIdx.z;
    const int b = bkv >> 2, kv = bkv & 3;
    const int t = threadIdx.x;

    {
        const int s = t >> 2, seg = t & 3;
        const unsigned short* src = qkv + (size_t)(b * SS + s0 + s) * NQKV +
                                    3072 + kv * DD + d0 + seg * 16;
        *(uint4*)&Lt[s][seg * 16]     = *(const uint4*)(src);
        *(uint4*)&Lt[s][seg * 16 + 8] = *(const uint4*)(src + 8);
    }
    __syncthreads();
    {
        const int d = t >> 2, sseg = t & 3;
        unsigned short tmp[16];
#pragma unroll
        for (int j = 0; j < 16; ++j) tmp[j] = Lt[sseg * 16 + j][d];
        unsigned short* dst = Vt + ((size_t)bkv * DD + d0 + d) * SS + s0 + sseg * 16;
        *(uint4*)(dst)     = *(uint4*)&tmp[0];
        *(uint4*)(dst + 8) = *(uint4*)&tmp[8];
    }
}

// ---------------------------------------------------------------------------
// bf16 MFMA flash attention (R2-verified); epilogue now writes bf16.
// ---------------------------------------------------------------------------
__global__ __launch_bounds__(256, 2)
void attn_mfma(const unsigned short* __restrict__ Qb,
               const unsigned short* __restrict__ Kb,
               const unsigned short* __restrict__ Vt,
               const int* __restrict__ am, unsigned short* __restrict__ O)
{
    __shared__ unsigned short Ks[32 * 256];    // [j][d], chunk-swizzled
    __shared__ unsigned short Vts[256 * 32];   // [d][j], chunk-swizzled
    __shared__ unsigned short Pl[4][16 * 40];  // per-wave P, row pad 40
    __shared__ int Ams[32];

    const int t = threadIdx.x, w = t >> 6, l = t & 63;
    const int g = l >> 4, q15 = l & 15;
    const int qb0 = blockIdx.x * 64, h = blockIdx.y, b = blockIdx.z;
    const int kvh = h >> 1;
    const int qrow = qb0 + w * 16 + q15;

    bf16x8 qf[8];
    {
        const unsigned short* qp = Qb + ((size_t)(b * SS + qrow) * HH + h) * DD + g * 8;
#pragma unroll
        for (int km = 0; km < 8; ++km) qf[km] = *(const bf16x8*)(qp + km * 32);
    }

    f32x4 oacc[16];
#pragma unroll
    for (int i = 0; i < 16; ++i) oacc[i] = (f32x4){0.f, 0.f, 0.f, 0.f};
    float mrow = -1e30f, lrow = 0.f;

    const int qlo = qb0 + w * 16, qhi = qlo + 15;
    int kstart = qb0 - 1024; if (kstart < 0) kstart = 0;
    const int kend = qb0 + 32;

    const int sj = t >> 3, sc = t & 7;

    for (int k0 = kstart; k0 <= kend; k0 += 32) {
        {
            const unsigned short* kp = Kb + ((size_t)(b * SS + k0 + sj) * KVN + kvh) * DD + sc * 32;
#pragma unroll
            for (int i = 0; i < 4; ++i) {
                const int cc = sc * 4 + i;
                *(uint4*)&Ks[sj * 256 + ((cc ^ (sj & 7)) * 8)] = *(const uint4*)(kp + i * 8);
            }
#pragma unroll
            for (int it = 0; it < 4; ++it) {
                const int d = it * 64 + (t >> 2), c = t & 3;
                const unsigned short* vp = Vt + ((size_t)(b * KVN + kvh) * DD + d) * SS + k0 + c * 8;
                *(uint4*)&Vts[d * 32 + ((c ^ (d & 3)) * 8)] = *(const uint4*)vp;
            }
            if (t < 32) Ams[t] = am[b * SS + k0 + t];
        }
        __syncthreads();

        if (k0 <= qhi && k0 + 31 >= qlo - (WINW - 1)) {
            float pv[8];
            int   okf[8];
            float tmax = -1e30f;
#pragma unroll
            for (int jb = 0; jb < 2; ++jb) {
                f32x4 sacc = (f32x4){0.f, 0.f, 0.f, 0.f};
                const int krow = jb * 16 + q15;
                const unsigned short* kbase = &Ks[krow * 256];
                const int kx = krow & 7;
#pragma unroll
                for (int km = 0; km < 8; ++km) {
                    const bf16x8 kf = *(const bf16x8*)(kbase + (((km * 4 + g) ^ kx) * 8));
                    sacc = __builtin_amdgcn_mfma_f32_16x16x32_bf16(kf, qf[km], sacc, 0, 0, 0);
                }
#pragma unroll
                for (int r = 0; r < 4; ++r) {
                    const int jgl = k0 + jb * 16 + g * 4 + r;
                    const bool ok = (jgl <= qrow) && (qrow - jgl < WINW) &&
                                    (Ams[jb * 16 + g * 4 + r] != 0);
                    const float val = ok ? sacc[r] : -1e30f;
                    okf[jb * 4 + r] = ok;
                    pv[jb * 4 + r] = val;
                    tmax = fmaxf(tmax, val);
                }
            }
            tmax = fmaxf(tmax, __shfl_xor(tmax, 16, 64));
            tmax = fmaxf(tmax, __shfl_xor(tmax, 32, 64));
            const float mnew = fmaxf(mrow, tmax);
            const float corr = __expf(mrow - mnew);
            float ps = 0.f;
#pragma unroll
            for (int i = 0; i < 8; ++i) {
                const float p = okf[i] ? __expf(pv[i] - mnew) : 0.f;
                pv[i] = p; ps += p;
            }
            ps += __shfl_xor(ps, 16, 64);
            ps += __shfl_xor(ps, 32, 64);
            lrow = lrow * corr + ps;
            mrow = mnew;

            unsigned short* Pw = &Pl[w][0];
#pragma unroll
            for (int jb = 0; jb < 2; ++jb) {
                const unsigned int u0 = (unsigned int)f2bf(pv[jb * 4 + 0]) |
                                        ((unsigned int)f2bf(pv[jb * 4 + 1]) << 16);
                const unsigned int u1 = (unsigned int)f2bf(pv[jb * 4 + 2]) |
                                        ((unsigned int)f2bf(pv[jb * 4 + 3]) << 16);
                *(unsigned int*)&Pw[q15 * 40 + jb * 16 + g * 4]     = u0;
                *(unsigned int*)&Pw[q15 * 40 + jb * 16 + g * 4 + 2] = u1;
            }

            if (__any(corr != 1.0f)) {
                const float c0 = __shfl(corr, g * 4 + 0, 64);
                const float c1 = __shfl(corr, g * 4 + 1, 64);
                const float c2 = __shfl(corr, g * 4 + 2, 64);
                const float c3 = __shfl(corr, g * 4 + 3, 64);
#pragma unroll
                for (int dm = 0; dm < 16; ++dm) {
                    oacc[dm][0] *= c0; oacc[dm][1] *= c1;
                    oacc[dm][2] *= c2; oacc[dm][3] *= c3;
                }
            }

            asm volatile("s_waitcnt lgkmcnt(0)" ::: "memory");
            const bf16x8 pa = *(const bf16x8*)&Pw[q15 * 40 + g * 8];
#pragma unroll
            for (int dm = 0; dm < 16; ++dm) {
                const int d = dm * 16 + q15;
                const bf16x8 vf = *(const bf16x8*)&Vts[d * 32 + ((g ^ (d & 3)) * 8)];
                oacc[dm] = __builtin_amdgcn_mfma_f32_16x16x32_bf16(pa, vf, oacc[dm], 0, 0, 0);
            }
        }
        __syncthreads();
    }

    float invl[4];
#pragma unroll
    for (int r = 0; r < 4; ++r) invl[r] = 1.0f / __shfl(lrow, g * 4 + r, 64);
#pragma unroll
    for (int dm = 0; dm < 16; ++dm) {
#pragma unroll
        for (int r = 0; r < 4; ++r) {
            const int qo = qb0 + w * 16 + g * 4 + r;
            O[((size_t)(b * SS + qo) * HH + h) * DD + dm * 16 + q15] =
                f2bf(oacc[dm][r] * invl[r]);
        }
    }
}

// ---------------------------------------------------------------------------
// Launch. Workspace (64 MiB, phase-reuse):
//   [ 0,16)  Xb bf16              -> Qb bf16 (after QKV GEMM)
//   [16,24)  Wt lower             -> Kb bf16
//   [24,32)  Wt upper             -> Vt bf16
//   [32,64)  qkv bf16 [4096][4096] -> Wot bf16 [32,40) + Ob bf16 [40,56)
//            (conv_wo runs AFTER norms+v_to_vt free the qkv region)
// ---------------------------------------------------------------------------
extern "C" void kernel_launch(void* const* d_in, const int* in_sizes, int n_in,
                              void* d_out, int out_size, void* d_ws, size_t ws_size,
                              hipStream_t stream)
{
    (void)in_sizes; (void)n_in; (void)out_size; (void)ws_size;

    const float* X  = (const float*)d_in[0];
    const float* cs = (const float*)d_in[1];
    const float* sn = (const float*)d_in[2];
    const int*   am = (const int*)d_in[3];
    const float* Wq = (const float*)d_in[4];
    const float* Wk = (const float*)d_in[5];
    const float* Wv = (const float*)d_in[6];
    const float* Wo = (const float*)d_in[7];
    const float* qw = (const float*)d_in[8];
    const float* kw = (const float*)d_in[9];
    float* out = (float*)d_out;

    char* ws = (char*)d_ws;
    unsigned short* Xb  = (unsigned short*)(ws);
    unsigned short* Qb  = (unsigned short*)(ws);                            // aliases Xb
    unsigned short* Wt  = (unsigned short*)(ws + (size_t)16 * 1024 * 1024);
    unsigned short* Kb  = (unsigned short*)(ws + (size_t)16 * 1024 * 1024); // aliases Wt
    unsigned short* Vt  = (unsigned short*)(ws + (size_t)24 * 1024 * 1024);
    unsigned short* qkv = (unsigned short*)(ws + (size_t)32 * 1024 * 1024);
    unsigned short* Wot = (unsigned short*)(ws + (size_t)32 * 1024 * 1024); // after qkv dead
    unsigned short* Ob  = (unsigned short*)(ws + (size_t)40 * 1024 * 1024); // after qkv dead

    const int M = BB * SS;   // 4096
    dim3 blk(256);

    // bf16 conversions (inputs)
    conv_x <<<dim3((M * EE) / (256 * 8)), blk, 0, stream>>>(X, Xb);
    conv_wt<<<dim3(EE / 64, NQKV / 64), blk, 0, stream>>>(Wq, Wk, Wv, Wt);

    // fused QKV projection (bf16 MFMA) -> qkv bf16
    gemm_bf16<false><<<dim3(NQKV / 128, M / 128), blk, 0, stream>>>(Xb, Wt, qkv, M, NQKV, EE);

    // norms (q-scale folded) + V transpose; these consume qkv
    rmsnorm_rope_qkv<KVN, 2048><<<dim3(M * KVN / 4), blk, 0, stream>>>(qkv, Kb, kw, cs, sn, 1.0f);
    rmsnorm_rope_qkv<HH, 0>    <<<dim3(M * HH  / 4), blk, 0, stream>>>(qkv, Qb, qw, cs, sn, 0.0625f);
    v_to_vt<<<dim3(SS / 64, DD / 64, BB * KVN), blk, 0, stream>>>(qkv, Vt);

    // qkv now dead: convert Wo into its region
    conv_wo<<<dim3(2048 / 64, 2048 / 64), blk, 0, stream>>>(Wo, Wot);

    // attention (bf16 MFMA) -> bf16 O
    attn_mfma<<<dim3(SS / 64, HH, BB), blk, 0, stream>>>(Qb, Kb, Vt, am, Ob);

    // output projection (bf16 MFMA, fp32 out)
    gemm_bf16<true><<<dim3(EE / 128, M / 128), blk, 0, stream>>>(Ob, Wot, out, M, EE, EE);
}